// Round 2
// baseline (3305.098 us; speedup 1.0000x reference)
//
#include <hip/hip_runtime.h>
#include <math.h>

#define B 2
#define S 1024
#define E 2048
#define H 16
#define HD 128
#define ROT 64
#define EPSN 1e-12f

using half8 = __attribute__((ext_vector_type(8))) _Float16;
using half4 = __attribute__((ext_vector_type(4))) _Float16;
using f32x4 = __attribute__((ext_vector_type(4))) float;

// ---------------------------------------------------------------------------
// fp32 -> fp16 conversion, 4 elems/thread
// ---------------------------------------------------------------------------
__global__ __launch_bounds__(256) void f2h_kernel(const float* __restrict__ x,
                                                  _Float16* __restrict__ y, int n4) {
    int i = blockIdx.x * 256 + threadIdx.x;
    if (i >= n4) return;
    float4 v = ((const float4*)x)[i];
    half4 h;
    h[0] = (_Float16)v.x; h[1] = (_Float16)v.y;
    h[2] = (_Float16)v.z; h[3] = (_Float16)v.w;
    ((half4*)y)[i] = h;
}

// ---------------------------------------------------------------------------
// NT-GEMM, f16 MFMA: C[m,n] = sum_k A[m,k] * W[n,k], fp32 out.
// 128x128 tile, BK=64, 256 threads (4 waves, 2x2 wave grid, 64x64/wave).
// MFMA 16x16x32_f16; A-frag: lane holds A[m=lane&15][k=(lane>>4)*8+j];
// C/D: row=(lane>>4)*4+r, col=lane&15  (m89/m92/m120-verified mappings).
// LDS layout [kq][m] -> frag reads & staging writes are 2-way max (free).
// ---------------------------------------------------------------------------
__global__ __launch_bounds__(256) void gemm_f16_nt(const _Float16* __restrict__ A,
                                                   const _Float16* __restrict__ W,
                                                   float* __restrict__ C,
                                                   int M, int N, int K) {
    __shared__ uint4 As[8][128];   // As[kq][m] = A[mBase+m][k0+kq*8 .. +7]
    __shared__ uint4 Ws[8][128];
    const int tid  = threadIdx.x;
    const int lane = tid & 63;
    const int wave = tid >> 6;
    const int wm   = (wave >> 1) * 64;
    const int wn   = (wave & 1) * 64;
    const int l15  = lane & 15;
    const int lq   = lane >> 4;    // 0..3
    const int mBase = blockIdx.y * 128;
    const int nBase = blockIdx.x * 128;

    f32x4 acc[4][4];
#pragma unroll
    for (int mt = 0; mt < 4; ++mt)
#pragma unroll
        for (int nt = 0; nt < 4; ++nt)
            acc[mt][nt] = (f32x4){0.f, 0.f, 0.f, 0.f};

    for (int k0 = 0; k0 < K; k0 += 64) {
#pragma unroll
        for (int j = 0; j < 4; ++j) {
            int f = tid + j * 256;          // 0..1023 over 128 m x 8 kq
            int m = f >> 3, kq = f & 7;
            As[kq][m] = *(const uint4*)&A[(size_t)(mBase + m) * K + k0 + kq * 8];
            Ws[kq][m] = *(const uint4*)&W[(size_t)(nBase + m) * K + k0 + kq * 8];
        }
        __syncthreads();
#pragma unroll
        for (int ks = 0; ks < 2; ++ks) {
            half8 af[4], wf[4];
#pragma unroll
            for (int t = 0; t < 4; ++t) {
                af[t] = *(const half8*)&As[ks * 4 + lq][wm + t * 16 + l15];
                wf[t] = *(const half8*)&Ws[ks * 4 + lq][wn + t * 16 + l15];
            }
#pragma unroll
            for (int mt = 0; mt < 4; ++mt)
#pragma unroll
                for (int nt = 0; nt < 4; ++nt)
                    acc[mt][nt] = __builtin_amdgcn_mfma_f32_16x16x32_f16(
                        af[mt], wf[nt], acc[mt][nt], 0, 0, 0);
        }
        __syncthreads();
    }

#pragma unroll
    for (int mt = 0; mt < 4; ++mt)
#pragma unroll
        for (int nt = 0; nt < 4; ++nt)
#pragma unroll
            for (int r = 0; r < 4; ++r) {
                int row = mBase + wm + mt * 16 + lq * 4 + r;
                int col = nBase + wn + nt * 16 + l15;
                C[(size_t)row * N + col] = acc[mt][nt][r];
            }
}

// ---------------------------------------------------------------------------
// counts[b][s] = inclusive prefix of (mask==0), parallel Hillis-Steele scan
// ---------------------------------------------------------------------------
__global__ __launch_bounds__(1024) void counts_kernel(const float* __restrict__ am,
                                                      float* __restrict__ counts) {
    __shared__ float buf[S];
    const int b = blockIdx.x, t = threadIdx.x;
    buf[t] = (am[b * S + t] == 0.f) ? 1.f : 0.f;
    __syncthreads();
    for (int off = 1; off < S; off <<= 1) {
        float add = (t >= off) ? buf[t - off] : 0.f;
        __syncthreads();
        buf[t] += add;
        __syncthreads();
    }
    counts[b * S + t] = buf[t];
}

// ---------------------------------------------------------------------------
// Rotary + L2 normalize + mask zeroing (in-place on q and k). Wave per (b,s,h).
// ---------------------------------------------------------------------------
__global__ __launch_bounds__(256) void rotary_norm(float* __restrict__ qb,
                                                   float* __restrict__ kb,
                                                   const float* __restrict__ am,
                                                   const int* __restrict__ pos) {
    const int wave = threadIdx.x >> 6;
    const int lane = threadIdx.x & 63;
    const int item = blockIdx.x * 4 + wave;      // < B*S*H
    const int b = item / (S * H);
    const int s = (item / H) % S;
    const int h = item % H;

    const float p = (float)pos[b * S + s];
    float co = 1.f, si = 0.f;
    if (lane < 32) {
        float ang = p * expf(-0.28782313662425574f * (float)lane); // ln(10000)/32
        sincosf(ang, &si, &co);
    }
    const float valid = (am[b * S + s] == 0.f) ? 1.f : 0.f;
    const size_t base = (size_t)(b * S + s) * E + h * HD;

    float* bufs[2] = {qb, kb};
#pragma unroll
    for (int a = 0; a < 2; ++a) {
        float* ptr = bufs[a];
        float x0 = ptr[base + 2 * lane];
        float x1 = ptr[base + 2 * lane + 1];
        float y0, y1;
        if (lane < 32) {
            y0 = x0 * co - x1 * si;
            y1 = x1 * co + x0 * si;
        } else {
            y0 = x0;
            y1 = x1;
        }
        float ss = y0 * y0 + y1 * y1;
#pragma unroll
        for (int off = 32; off > 0; off >>= 1)
            ss += __shfl_xor(ss, off);
        float scale = valid / fmaxf(sqrtf(ss), EPSN);
        ptr[base + 2 * lane]     = y0 * scale;
        ptr[base + 2 * lane + 1] = y1 * scale;
    }
}

// ---------------------------------------------------------------------------
// v *= mask / max(counts^sigmoid(nc), 1)
// ---------------------------------------------------------------------------
__global__ __launch_bounds__(256) void vscale(float* __restrict__ v,
                                              const float* __restrict__ am,
                                              const float* __restrict__ counts,
                                              const float* __restrict__ nc) {
    int idx = blockIdx.x * 256 + threadIdx.x;    // < B*S*E
    int b = idx / (S * E);
    int rem = idx % (S * E);
    int s = rem / E;
    int h = (rem % E) / HD;
    float sig = 1.f / (1.f + expf(-nc[h]));
    float cnt = counts[b * S + s];
    float denom = fmaxf(powf(cnt, sig), 1.f);
    float m = (am[b * S + s] == 0.f) ? 1.f : 0.f;
    v[idx] = v[idx] * m / denom;
}

// ---------------------------------------------------------------------------
// Attention per (b,h): O = tril(Qn Kn^T) @ Vs, fp32, fp16 output.
// 64-query tile, 32-key chunks. Register tiles: scores 4q x 2k (strided k),
// PV 4q x 8d (split d / d+64). LDS 74.5 KB -> 2 blocks/CU. qt reversed.
// ---------------------------------------------------------------------------
__global__ __launch_bounds__(256) void attn(const float* __restrict__ q,
                                            const float* __restrict__ k,
                                            const float* __restrict__ v,
                                            _Float16* __restrict__ o) {
    __shared__ float Qs[64][132];
    __shared__ float Ks[32][132];
    __shared__ float Vs[32][132];
    __shared__ float Ss[64][34];

    const int qt = (int)gridDim.x - 1 - (int)blockIdx.x;   // heavy blocks first
    const int bh = blockIdx.y;
    const int b = bh >> 4, h = bh & 15;
    const int tid = threadIdx.x;
    const int tx = tid & 15, ty = tid >> 4;
    const int qBase = qt * 64;
    const size_t base_bh = (size_t)b * S * E + (size_t)h * HD;

    // stage Q tile: 64 x 128 = 2048 float4s, 8/thread
#pragma unroll
    for (int j = 0; j < 8; ++j) {
        int f = tid + j * 256;
        int r = f >> 5, c4 = f & 31;
        *(float4*)&Qs[r][c4 * 4] =
            *(const float4*)&q[base_bh + (size_t)(qBase + r) * E + c4 * 4];
    }

    float acc[4][8] = {};
    const int nkc = 2 * qt + 2;
    for (int kc = 0; kc < nkc; ++kc) {
        const int kBase = kc * 32;
        __syncthreads();   // prev-iter Ks/Vs/Ss reads done (also covers Qs staging)
#pragma unroll
        for (int j = 0; j < 4; ++j) {
            int f = tid + j * 256;
            int r = f >> 5, c4 = f & 31;
            *(float4*)&Ks[r][c4 * 4] =
                *(const float4*)&k[base_bh + (size_t)(kBase + r) * E + c4 * 4];
            *(float4*)&Vs[r][c4 * 4] =
                *(const float4*)&v[base_bh + (size_t)(kBase + r) * E + c4 * 4];
        }
        __syncthreads();

        // scores: q rows ty*4+i, k cols tx and tx+16
        float sc[4][2] = {};
#pragma unroll
        for (int d0 = 0; d0 < HD; d0 += 4) {
            float4 b0 = *(const float4*)&Ks[tx][d0];
            float4 b1 = *(const float4*)&Ks[tx + 16][d0];
#pragma unroll
            for (int i = 0; i < 4; ++i) {
                float4 a = *(const float4*)&Qs[ty * 4 + i][d0];
                sc[i][0] += a.x * b0.x + a.y * b0.y + a.z * b0.z + a.w * b0.w;
                sc[i][1] += a.x * b1.x + a.y * b1.y + a.z * b1.z + a.w * b1.w;
            }
        }
#pragma unroll
        for (int i = 0; i < 4; ++i)
#pragma unroll
            for (int jj = 0; jj < 2; ++jj) {
                int qg = qBase + ty * 4 + i;
                int kg = kBase + tx + 16 * jj;
                Ss[ty * 4 + i][tx + 16 * jj] = (kg <= qg) ? sc[i][jj] : 0.f;
            }
        __syncthreads();

        // PV: 4q x 8d (d = tx*4..+3 and 64+tx*4..+3), 2 keys per step
#pragma unroll
        for (int kk = 0; kk < 16; ++kk) {
            float4 va0 = *(const float4*)&Vs[2 * kk][tx * 4];
            float4 va1 = *(const float4*)&Vs[2 * kk][64 + tx * 4];
            float4 vb0 = *(const float4*)&Vs[2 * kk + 1][tx * 4];
            float4 vb1 = *(const float4*)&Vs[2 * kk + 1][64 + tx * 4];
#pragma unroll
            for (int i = 0; i < 4; ++i) {
                float2 s2 = *(const float2*)&Ss[ty * 4 + i][2 * kk];
                acc[i][0] += s2.x * va0.x + s2.y * vb0.x;
                acc[i][1] += s2.x * va0.y + s2.y * vb0.y;
                acc[i][2] += s2.x * va0.z + s2.y * vb0.z;
                acc[i][3] += s2.x * va0.w + s2.y * vb0.w;
                acc[i][4] += s2.x * va1.x + s2.y * vb1.x;
                acc[i][5] += s2.x * va1.y + s2.y * vb1.y;
                acc[i][6] += s2.x * va1.z + s2.y * vb1.z;
                acc[i][7] += s2.x * va1.w + s2.y * vb1.w;
            }
        }
    }

    // write O as fp16 (feeds the out-projection GEMM)
#pragma unroll
    for (int i = 0; i < 4; ++i) {
        size_t rowoff = base_bh + (size_t)(qBase + ty * 4 + i) * E;
        half4 h0, h1;
#pragma unroll
        for (int d = 0; d < 4; ++d) {
            h0[d] = (_Float16)acc[i][d];
            h1[d] = (_Float16)acc[i][4 + d];
        }
        *(half4*)&o[rowoff + tx * 4] = h0;
        *(half4*)&o[rowoff + 64 + tx * 4] = h1;
    }
}

// ---------------------------------------------------------------------------
extern "C" void kernel_launch(void* const* d_in, const int* in_sizes, int n_in,
                              void* d_out, int out_size, void* d_ws, size_t ws_size,
                              hipStream_t stream) {
    (void)in_sizes; (void)n_in; (void)out_size; (void)ws_size;
    const float* hs = (const float*)d_in[0];
    const float* wq = (const float*)d_in[1];
    const float* wk = (const float*)d_in[2];
    const float* wv = (const float*)d_in[3];
    const float* wo = (const float*)d_in[4];
    const float* nc = (const float*)d_in[5];
    const float* am = (const float*)d_in[6];
    const int*  pos = (const int*)d_in[7];
    float* out = (float*)d_out;

    const size_t act = (size_t)B * S * E;           // 4,194,304 (== E*E)
    float* qb  = (float*)d_ws;
    float* kb  = qb + act;
    float* vb  = kb + act;
    float* cnt = vb + act;                          // B*S floats
    _Float16* hsb = (_Float16*)(cnt + B * S);
    _Float16* wqb = hsb + act;
    _Float16* wkb = wqb + act;
    _Float16* wvb = wkb + act;
    _Float16* wob = wvb + act;
    _Float16* abb = wob + act;                      // attn output, fp16
    // total ws: 3*16.78MB + 8KB + 6*8.39MB ~= 101 MB

    const int n4 = (int)(act / 4);                  // 1,048,576
    const int cgrid = n4 / 256;                     // 4096
    f2h_kernel<<<cgrid, 256, 0, stream>>>(hs, hsb, n4);
    f2h_kernel<<<cgrid, 256, 0, stream>>>(wq, wqb, n4);
    f2h_kernel<<<cgrid, 256, 0, stream>>>(wk, wkb, n4);
    f2h_kernel<<<cgrid, 256, 0, stream>>>(wv, wvb, n4);
    f2h_kernel<<<cgrid, 256, 0, stream>>>(wo, wob, n4);

    dim3 ggrid(E / 128, (B * S) / 128);             // 16 x 16
    gemm_f16_nt<<<ggrid, 256, 0, stream>>>(hsb, wqb, qb, B * S, E, E);
    gemm_f16_nt<<<ggrid, 256, 0, stream>>>(hsb, wkb, kb, B * S, E, E);
    gemm_f16_nt<<<ggrid, 256, 0, stream>>>(hsb, wvb, vb, B * S, E, E);

    counts_kernel<<<B, S, 0, stream>>>(am, cnt);
    rotary_norm<<<(B * S * H) / 4, 256, 0, stream>>>(qb, kb, am, pos);
    vscale<<<(B * S * E) / 256, 256, 0, stream>>>(vb, am, cnt, nc);

    attn<<<dim3(S / 64, B * H), 256, 0, stream>>>(qb, kb, vb, abb);

    gemm_f16_nt<<<ggrid, 256, 0, stream>>>(abb, wob, out, B * S, E, E);
}

// Round 3
// 450.848 us; speedup vs baseline: 7.3308x; 7.3308x over previous
//
#include <hip/hip_runtime.h>
#include <math.h>

#define B 2
#define S 1024
#define E 2048
#define H 16
#define HD 128
#define ROT 64
#define EPSN 1e-12f

using half8 = __attribute__((ext_vector_type(8))) _Float16;
using half4 = __attribute__((ext_vector_type(4))) _Float16;
using half2 = __attribute__((ext_vector_type(2))) _Float16;
using f32x4 = __attribute__((ext_vector_type(4))) float;

// ---------------------------------------------------------------------------
// fp32 -> fp16 conversion, 4 elems/thread
// ---------------------------------------------------------------------------
__global__ __launch_bounds__(256) void f2h_kernel(const float* __restrict__ x,
                                                  _Float16* __restrict__ y, int n4) {
    int i = blockIdx.x * 256 + threadIdx.x;
    if (i >= n4) return;
    float4 v = ((const float4*)x)[i];
    half4 h;
    h[0] = (_Float16)v.x; h[1] = (_Float16)v.y;
    h[2] = (_Float16)v.z; h[3] = (_Float16)v.w;
    ((half4*)y)[i] = h;
}

// ---------------------------------------------------------------------------
// NT-GEMM, f16 MFMA: C[m,n] = sum_k A[m,k] * W[n,k], OutT out (float or fp16).
// 128x128 tile, BK=64, 256 threads (4 waves, 2x2), MFMA 16x16x32_f16.
// A-frag: lane holds A[m=lane&15][k=(lane>>4)*8+j]; C/D: row=(lane>>4)*4+r,
// col=lane&15 (verified round 2).
// ---------------------------------------------------------------------------
template <typename OutT>
__global__ __launch_bounds__(256) void gemm_f16_nt(const _Float16* __restrict__ A,
                                                   const _Float16* __restrict__ W,
                                                   OutT* __restrict__ C,
                                                   int M, int N, int K) {
    __shared__ uint4 As[8][128];   // As[kq][m] = A[mBase+m][k0+kq*8 .. +7]
    __shared__ uint4 Ws[8][128];
    const int tid  = threadIdx.x;
    const int lane = tid & 63;
    const int wave = tid >> 6;
    const int wm   = (wave >> 1) * 64;
    const int wn   = (wave & 1) * 64;
    const int l15  = lane & 15;
    const int lq   = lane >> 4;    // 0..3
    const int mBase = blockIdx.y * 128;
    const int nBase = blockIdx.x * 128;

    f32x4 acc[4][4];
#pragma unroll
    for (int mt = 0; mt < 4; ++mt)
#pragma unroll
        for (int nt = 0; nt < 4; ++nt)
            acc[mt][nt] = (f32x4){0.f, 0.f, 0.f, 0.f};

    for (int k0 = 0; k0 < K; k0 += 64) {
#pragma unroll
        for (int j = 0; j < 4; ++j) {
            int f = tid + j * 256;          // 0..1023 over 128 m x 8 kq
            int m = f >> 3, kq = f & 7;
            As[kq][m] = *(const uint4*)&A[(size_t)(mBase + m) * K + k0 + kq * 8];
            Ws[kq][m] = *(const uint4*)&W[(size_t)(nBase + m) * K + k0 + kq * 8];
        }
        __syncthreads();
#pragma unroll
        for (int ks = 0; ks < 2; ++ks) {
            half8 af[4], wf[4];
#pragma unroll
            for (int t = 0; t < 4; ++t) {
                af[t] = *(const half8*)&As[ks * 4 + lq][wm + t * 16 + l15];
                wf[t] = *(const half8*)&Ws[ks * 4 + lq][wn + t * 16 + l15];
            }
#pragma unroll
            for (int mt = 0; mt < 4; ++mt)
#pragma unroll
                for (int nt = 0; nt < 4; ++nt)
                    acc[mt][nt] = __builtin_amdgcn_mfma_f32_16x16x32_f16(
                        af[mt], wf[nt], acc[mt][nt], 0, 0, 0);
        }
        __syncthreads();
    }

#pragma unroll
    for (int mt = 0; mt < 4; ++mt)
#pragma unroll
        for (int nt = 0; nt < 4; ++nt)
#pragma unroll
            for (int r = 0; r < 4; ++r) {
                int row = mBase + wm + mt * 16 + lq * 4 + r;
                int col = nBase + wn + nt * 16 + l15;
                C[(size_t)row * N + col] = (OutT)acc[mt][nt][r];
            }
}

// ---------------------------------------------------------------------------
// counts[b][s] = inclusive prefix of (mask==0), parallel scan
// ---------------------------------------------------------------------------
__global__ __launch_bounds__(1024) void counts_kernel(const float* __restrict__ am,
                                                      float* __restrict__ counts) {
    __shared__ float buf[S];
    const int b = blockIdx.x, t = threadIdx.x;
    buf[t] = (am[b * S + t] == 0.f) ? 1.f : 0.f;
    __syncthreads();
    for (int off = 1; off < S; off <<= 1) {
        float add = (t >= off) ? buf[t - off] : 0.f;
        __syncthreads();
        buf[t] += add;
        __syncthreads();
    }
    counts[b * S + t] = buf[t];
}

// ---------------------------------------------------------------------------
// Rotary + L2 normalize + mask, fp16 in (b,s,E) -> fp16 out (b,h,s,d).
// One wave per (b,s,h); lane l handles dims 2l, 2l+1.
// ---------------------------------------------------------------------------
__global__ __launch_bounds__(256) void rotary_norm(const _Float16* __restrict__ qin,
                                                   const _Float16* __restrict__ kin,
                                                   _Float16* __restrict__ qh,
                                                   _Float16* __restrict__ kh,
                                                   const float* __restrict__ am,
                                                   const int* __restrict__ pos) {
    const int wave = threadIdx.x >> 6;
    const int lane = threadIdx.x & 63;
    const int item = blockIdx.x * 4 + wave;      // < B*S*H
    const int b = item / (S * H);
    const int s = (item / H) % S;
    const int h = item % H;

    const float p = (float)pos[b * S + s];
    float co = 1.f, si = 0.f;
    if (lane < 32) {
        float ang = p * expf(-0.28782313662425574f * (float)lane); // ln(10000)/32
        sincosf(ang, &si, &co);
    }
    const float valid = (am[b * S + s] == 0.f) ? 1.f : 0.f;
    const size_t ibase = (size_t)(b * S + s) * E + h * HD;
    const size_t obase = ((size_t)(b * H + h) * S + s) * HD;

    const _Float16* ins[2]  = {qin, kin};
    _Float16*       outs[2] = {qh, kh};
#pragma unroll
    for (int a = 0; a < 2; ++a) {
        half2 xin = *(const half2*)&ins[a][ibase + 2 * lane];
        float x0 = (float)xin[0], x1 = (float)xin[1];
        float y0, y1;
        if (lane < 32) {
            y0 = x0 * co - x1 * si;
            y1 = x1 * co + x0 * si;
        } else {
            y0 = x0;
            y1 = x1;
        }
        float ss = y0 * y0 + y1 * y1;
#pragma unroll
        for (int off = 32; off > 0; off >>= 1)
            ss += __shfl_xor(ss, off);
        float scale = valid / fmaxf(sqrtf(ss), EPSN);
        half2 xo;
        xo[0] = (_Float16)(y0 * scale);
        xo[1] = (_Float16)(y1 * scale);
        *(half2*)&outs[a][obase + 2 * lane] = xo;
    }
}

// ---------------------------------------------------------------------------
// vprep: v (b,s,E) fp16 -> scaled V^T (b,h,d,s) fp16.
// scale = mask / max(counts^sigmoid(nc[h]), 1). LDS-tiled transpose, 64-s tiles.
// ---------------------------------------------------------------------------
__global__ __launch_bounds__(256) void vprep(const _Float16* __restrict__ v,
                                             _Float16* __restrict__ vt,
                                             const float* __restrict__ am,
                                             const float* __restrict__ counts,
                                             const float* __restrict__ nc) {
    __shared__ _Float16 T[HD][72];     // [d][s] pad 8
    __shared__ float sscale[64];
    const int bh = blockIdx.y;
    const int b = bh >> 4, h = bh & 15;
    const int s0 = blockIdx.x * 64;
    const int tid = threadIdx.x;

    if (tid < 64) {
        int s = s0 + tid;
        float sig = 1.f / (1.f + expf(-nc[h]));
        float denom = fmaxf(powf(counts[b * S + s], sig), 1.f);
        float m = (am[b * S + s] == 0.f) ? 1.f : 0.f;
        sscale[tid] = m / denom;
    }
    __syncthreads();

    // read 64 s x 128 d (as 8-fp16 groups): 64*16 = 1024 uint4, 4/thread
#pragma unroll
    for (int j = 0; j < 4; ++j) {
        int f = tid + j * 256;
        int s = f >> 4, c8 = f & 15;
        half8 x = *(const half8*)&v[(size_t)(b * S + s0 + s) * E + h * HD + c8 * 8];
        float sc = sscale[s];
#pragma unroll
        for (int i = 0; i < 8; ++i)
            T[c8 * 8 + i][s] = (_Float16)((float)x[i] * sc);
    }
    __syncthreads();

    // write 128 d rows x 64 s, coalesced 16B: 128*8 = 1024 uint4, 4/thread
#pragma unroll
    for (int j = 0; j < 4; ++j) {
        int f = tid + j * 256;
        int d = f >> 3, c8 = f & 7;
        *(uint4*)&vt[((size_t)bh * HD + d) * S + s0 + c8 * 8] =
            *(const uint4*)&T[d][c8 * 8];
    }
}

// ---------------------------------------------------------------------------
// MFMA attention: O = tril(Q K^T) @ Vs  (no softmax), fp16 in/out, fp32 acc.
// qh,kh: (b,h,s,d); vt: (b,h,d,s); o: (b,s,E).
// Block = (b,h) x 64-q tile, 4 waves, wave w owns q rows [w*16, w*16+16).
// K chunks of 64. P round-trips through LDS (C-layout -> A-frag, m120).
// ---------------------------------------------------------------------------
__global__ __launch_bounds__(256) void attn_mfma(const _Float16* __restrict__ qh,
                                                 const _Float16* __restrict__ kh,
                                                 const _Float16* __restrict__ vt,
                                                 _Float16* __restrict__ o) {
    __shared__ _Float16 Ks[64][136];   // [key][d], +8 pad
    __shared__ _Float16 Vs[HD][72];    // [d][key], +8 pad
    __shared__ _Float16 Ps[64][72];    // [q][key], +8 pad

    const int qt = (int)gridDim.x - 1 - (int)blockIdx.x;   // heavy first
    const int bh = blockIdx.y;
    const int b = bh >> 4, h = bh & 15;
    const int tid = threadIdx.x;
    const int lane = tid & 63;
    const int w = tid >> 6;
    const int l15 = lane & 15;
    const int lq = lane >> 4;
    const int qBase = qt * 64;
    const size_t sd_base = (size_t)bh * S * HD;   // qh/kh/(vt) base for this (b,h)

    // Q A-frags in registers: rows qBase + w*16 + l15, 4 k-steps over d=0..127
    half8 qf[4];
#pragma unroll
    for (int ks = 0; ks < 4; ++ks)
        qf[ks] = *(const half8*)&qh[sd_base + (size_t)(qBase + w * 16 + l15) * HD +
                                    ks * 32 + lq * 8];

    f32x4 oacc[8];
#pragma unroll
    for (int dt = 0; dt < 8; ++dt)
        oacc[dt] = (f32x4){0.f, 0.f, 0.f, 0.f};

    const int nkc = qt + 1;
    for (int kc = 0; kc < nkc; ++kc) {
        const int kBase = kc * 64;
        __syncthreads();   // prev-iter Ks/Vs reads complete
        // stage K chunk: 64 keys x 128 d, 1024 uint4, 4/thread
#pragma unroll
        for (int j = 0; j < 4; ++j) {
            int f = tid + j * 256;
            int r = f >> 4, c8 = f & 15;
            *(uint4*)&Ks[r][c8 * 8] =
                *(const uint4*)&kh[sd_base + (size_t)(kBase + r) * HD + c8 * 8];
        }
        // stage V^T chunk: 128 d x 64 keys, 1024 uint4, 4/thread
#pragma unroll
        for (int j = 0; j < 4; ++j) {
            int f = tid + j * 256;
            int r = f >> 3, c8 = f & 7;
            *(uint4*)&Vs[r][c8 * 8] =
                *(const uint4*)&vt[sd_base + (size_t)r * S + kBase + c8 * 8];
        }
        __syncthreads();

        // QK^T: 4 key-tiles x 4 k-steps
        f32x4 sacc[4];
#pragma unroll
        for (int nt = 0; nt < 4; ++nt)
            sacc[nt] = (f32x4){0.f, 0.f, 0.f, 0.f};
#pragma unroll
        for (int nt = 0; nt < 4; ++nt)
#pragma unroll
            for (int ks = 0; ks < 4; ++ks) {
                half8 kf = *(const half8*)&Ks[nt * 16 + l15][ks * 32 + lq * 8];
                sacc[nt] = __builtin_amdgcn_mfma_f32_16x16x32_f16(qf[ks], kf,
                                                                  sacc[nt], 0, 0, 0);
            }

        // causal mask + fp16 convert + P to LDS (C-layout write, own rows only)
#pragma unroll
        for (int nt = 0; nt < 4; ++nt)
#pragma unroll
            for (int r = 0; r < 4; ++r) {
                int qg = qBase + w * 16 + lq * 4 + r;
                int kg = kBase + nt * 16 + l15;
                float sv = (kg <= qg) ? sacc[nt][r] : 0.f;
                Ps[w * 16 + lq * 4 + r][nt * 16 + l15] = (_Float16)sv;
            }
        // Ps rows [w*16, w*16+16) are written and read by wave w only -> the
        // compiler-inserted lgkmcnt ordering suffices; no barrier needed.

        // PV: A-frags from Ps, B-frags from Vs (V^T rows = d)
        half8 pf[2];
        pf[0] = *(const half8*)&Ps[w * 16 + l15][lq * 8];
        pf[1] = *(const half8*)&Ps[w * 16 + l15][32 + lq * 8];
#pragma unroll
        for (int dt = 0; dt < 8; ++dt)
#pragma unroll
            for (int ks = 0; ks < 2; ++ks) {
                half8 vf = *(const half8*)&Vs[dt * 16 + l15][ks * 32 + lq * 8];
                oacc[dt] = __builtin_amdgcn_mfma_f32_16x16x32_f16(pf[ks], vf,
                                                                  oacc[dt], 0, 0, 0);
            }
    }

    // write O (b,s,E) fp16: row = qBase+w*16+lq*4+r, d = dt*16+l15
#pragma unroll
    for (int dt = 0; dt < 8; ++dt)
#pragma unroll
        for (int r = 0; r < 4; ++r) {
            size_t off = (size_t)(b * S + qBase + w * 16 + lq * 4 + r) * E +
                         h * HD + dt * 16 + l15;
            o[off] = (_Float16)oacc[dt][r];
        }
}

// ---------------------------------------------------------------------------
extern "C" void kernel_launch(void* const* d_in, const int* in_sizes, int n_in,
                              void* d_out, int out_size, void* d_ws, size_t ws_size,
                              hipStream_t stream) {
    (void)in_sizes; (void)n_in; (void)out_size; (void)ws_size;
    const float* hs = (const float*)d_in[0];
    const float* wq = (const float*)d_in[1];
    const float* wk = (const float*)d_in[2];
    const float* wv = (const float*)d_in[3];
    const float* wo = (const float*)d_in[4];
    const float* nc = (const float*)d_in[5];
    const float* am = (const float*)d_in[6];
    const int*  pos = (const int*)d_in[7];
    float* out = (float*)d_out;

    const size_t act = (size_t)B * S * E;           // 4,194,304 (== E*E)
    _Float16* hsb = (_Float16*)d_ws;
    _Float16* wqb = hsb + act;
    _Float16* wkb = wqb + act;
    _Float16* wvb = wkb + act;
    _Float16* wob = wvb + act;
    _Float16* qb16 = wob + act;                     // QKV proj outputs, fp16
    _Float16* kb16 = qb16 + act;
    _Float16* vb16 = kb16 + act;
    _Float16* qhh = vb16 + act;                     // (b,h,s,d)
    _Float16* khh = qhh + act;
    _Float16* vtt = khh + act;                      // (b,h,d,s)
    _Float16* abb = vtt + act;                      // attn out (b,s,E)
    float* cnt = (float*)(abb + act);               // B*S floats
    // total ws: 12 * 8.39MB + 8KB ~= 100.7 MB

    const int n4 = (int)(act / 4);                  // 1,048,576
    const int cgrid = n4 / 256;                     // 4096
    f2h_kernel<<<cgrid, 256, 0, stream>>>(hs, hsb, n4);
    f2h_kernel<<<cgrid, 256, 0, stream>>>(wq, wqb, n4);
    f2h_kernel<<<cgrid, 256, 0, stream>>>(wk, wkb, n4);
    f2h_kernel<<<cgrid, 256, 0, stream>>>(wv, wvb, n4);
    f2h_kernel<<<cgrid, 256, 0, stream>>>(wo, wob, n4);

    dim3 ggrid(E / 128, (B * S) / 128);             // 16 x 16
    gemm_f16_nt<_Float16><<<ggrid, 256, 0, stream>>>(hsb, wqb, qb16, B * S, E, E);
    gemm_f16_nt<_Float16><<<ggrid, 256, 0, stream>>>(hsb, wkb, kb16, B * S, E, E);
    gemm_f16_nt<_Float16><<<ggrid, 256, 0, stream>>>(hsb, wvb, vb16, B * S, E, E);

    counts_kernel<<<B, S, 0, stream>>>(am, cnt);
    rotary_norm<<<(B * S * H) / 4, 256, 0, stream>>>(qb16, kb16, qhh, khh, am, pos);
    vprep<<<dim3(S / 64, B * H), 256, 0, stream>>>(vb16, vtt, am, cnt, nc);

    attn_mfma<<<dim3(S / 64, B * H), 256, 0, stream>>>(qhh, khh, vtt, abb);

    gemm_f16_nt<float><<<ggrid, 256, 0, stream>>>(abb, wob, out, B * S, E, E);
}